// Round 4
// baseline (382.797 us; speedup 1.0000x reference)
//
#include <hip/hip_runtime.h>

#define DEV __device__ __forceinline__

typedef _Float16 half8  __attribute__((ext_vector_type(8)));
typedef _Float16 half4h __attribute__((ext_vector_type(4)));
typedef float    f32x4  __attribute__((ext_vector_type(4)));

static constexpr int Bb = 8;
static constexpr int Ff = 16;
static constexpr int Pp = 196;
static constexpr int Dd = 768;
static constexpr int Hh = 12;
static constexpr int HD = 64;
static constexpr int Nn = 3136;    // F*P tokens per batch
static constexpr int NC = 392;     // Nn/8 token chunks per batch

#define MFMA(a, b, c) __builtin_amdgcn_mfma_f32_16x16x32_f16(a, b, c, 0, 0, 0)

DEV void gll16(const _Float16* g, _Float16* l) {
  __builtin_amdgcn_global_load_lds(
      (__attribute__((address_space(1))) void*)(g),
      (__attribute__((address_space(3))) void*)(l), 16, 0, 0);
}

// LDS-only fence: wait DS ops, compiler memory barrier. Does NOT drain vmcnt,
// so global loads stay in flight across it.
DEV void lds_fence() { asm volatile("s_waitcnt lgkmcnt(0)" ::: "memory"); }

// ---------------------------------------------------------------- convert
__global__ __launch_bounds__(256) void cvt_all(const float* __restrict__ x,
                                               const float* __restrict__ wq,
                                               const float* __restrict__ wp,
                                               _Float16* __restrict__ xh,
                                               _Float16* __restrict__ wqh,
                                               _Float16* __restrict__ wph) {
  const int NX = 4816896, NQ = 442368;  // in f32x4 units
  int i = blockIdx.x * 256 + threadIdx.x;
  const float* s;
  _Float16* d;
  int j;
  if (i < NX) { s = x; d = xh; j = i; }
  else if (i < NX + NQ) { s = wq; d = wqh; j = i - NX; }
  else { s = wp; d = wph; j = i - NX - NQ; }
  f32x4 v = ((const f32x4*)s)[j];
  half4h h;
  h.x = (_Float16)v.x; h.y = (_Float16)v.y;
  h.z = (_Float16)v.z; h.w = (_Float16)v.w;
  ((half4h*)d)[j] = h;
}

// ---------------------------------------------------------------- QKV GEMM
// 256x256 tile, 8 waves (2M x 4N), BK=32, ring-4 LDS (128 KiB) with counted
// vmcnt: tile t computes slot t%4 while tile t+3 stages into slot (t+3)%4.
// End-of-tile s_waitcnt vmcnt(8) retires exactly tile t+1 (tiles t+2, t+3
// stay in flight = ~2 K-tiles of latency slack); never drains to 0 until the
// tail. Slot (t+3)%4 was last read at tile t-1, barrier-ordered before the
// stage issue -> no clobber. ds_read<->MFMA lgkm waits are left to the
// compiler (it schedules those well); 12 x b128 reads feed 32 MFMA per tile
// (vs 8 reads / 16 MFMA at 128^2) -> 25% less LDS traffic per MFMA.
// Swizzle identical to the proven 0-conflict pattern. Epilogue = R1's
// verified 256^2 two-half transpose.
__global__ __launch_bounds__(512, 1) void gemm_qkv(const _Float16* __restrict__ X,
                                                   const _Float16* __restrict__ W,
                                                   _Float16* __restrict__ Q8,
                                                   _Float16* __restrict__ K8,
                                                   _Float16* __restrict__ V8) {
  __shared__ __align__(16) _Float16 smem[4 * 16384];  // 128 KiB ring; epilogue reuses
  const int tid = threadIdx.x;                        // 0..511
  const int lane = tid & 63, wid = tid >> 6;
  const int l15 = lane & 15, quad = lane >> 4;
  // bijective XCD-chunked swizzle over 882 = 8*110 + 2 (m204 variant)
  const int L = blockIdx.x;
  const int xcd = L & 7, idx = L >> 3;
  const int v = xcd * 110 + (xcd < 2 ? xcd : 2) + idx;
  const int bx = v % 9, by = v / 9;
  const int row0 = by * 256;
  const int e0 = bx * 256;
  const int wm = (wid >> 2) * 128, wn = (wid & 3) * 64;

  const _Float16* Ag = X + (size_t)row0 * Dd;
  const _Float16* Bg = W + (size_t)e0 * Dd;

  f32x4 acc[8][4];
#pragma unroll
  for (int i = 0; i < 8; ++i)
#pragma unroll
    for (int j = 0; j < 4; ++j) acc[i][j] = (f32x4)0.0f;

  // staging: 256 rows x 4 chunks per matrix per tile; 512 threads -> 2 each
  const int c0 = tid, c1 = tid + 512;
  const int r0s = c0 >> 2, o0 = ((c0 & 3) ^ ((r0s >> 1) & 3)) * 8;
  const int r1s = c1 >> 2, o1 = ((c1 & 3) ^ ((r1s >> 1) & 3)) * 8;
  const int csel = (quad ^ ((l15 >> 1) & 3)) * 8;

  auto stage = [&](int t) {
    const int kn = t * 32;
    _Float16* An = smem + (t & 3) * 16384;
    _Float16* Bn = An + 8192;
    gll16(Ag + (size_t)r0s * Dd + kn + o0, An + c0 * 8);
    gll16(Ag + (size_t)r1s * Dd + kn + o1, An + c1 * 8);
    gll16(Bg + (size_t)r0s * Dd + kn + o0, Bn + c0 * 8);
    gll16(Bg + (size_t)r1s * Dd + kn + o1, Bn + c1 * 8);
  };

  // prologue: stage tiles 0,1,2; wait tile 0 only (8 loads stay in flight)
  stage(0);
  stage(1);
  stage(2);
  asm volatile("s_waitcnt vmcnt(8)" ::: "memory");
  asm volatile("s_barrier" ::: "memory");

  auto tile = [&](int T, int SL, bool STG, int WV) {
    if (STG) stage(T + 3);
    const _Float16* As_ = smem + SL * 16384;
    const _Float16* Bs_ = As_ + 8192;
    half8 af[8], bf[4];
#pragma unroll
    for (int m = 0; m < 8; ++m)
      af[m] = *(const half8*)(As_ + (wm + m * 16 + l15) * 32 + csel);
#pragma unroll
    for (int n = 0; n < 4; ++n)
      bf[n] = *(const half8*)(Bs_ + (wn + n * 16 + l15) * 32 + csel);
    __builtin_amdgcn_s_setprio(1);
#pragma unroll
    for (int m = 0; m < 8; ++m)
#pragma unroll
      for (int n = 0; n < 4; ++n) acc[m][n] = MFMA(af[m], bf[n], acc[m][n]);
    __builtin_amdgcn_s_setprio(0);
    if (WV == 8)      asm volatile("s_waitcnt vmcnt(8)" ::: "memory");
    else if (WV == 4) asm volatile("s_waitcnt vmcnt(4)" ::: "memory");
    else if (WV == 0) asm volatile("s_waitcnt vmcnt(0)" ::: "memory");
    if (WV >= 0) asm volatile("s_barrier" ::: "memory");
  };

#pragma unroll
  for (int g = 0; g < 6; ++g) {
#pragma unroll
    for (int u = 0; u < 4; ++u) {
      const int T = g * 4 + u;
      tile(T, u, T < 21, T < 21 ? 8 : (T == 21 ? 4 : (T == 22 ? 0 : -1)));
    }
  }

  // -------- epilogue (R1-verified): reuse LDS, two 128-row halves
  __syncthreads();
  const int tsel = e0 / Dd;        // 0=Q, 1=K, 2=V
  const int eb = e0 - tsel * Dd;   // 0/256/512 within the matrix
  if (tsel == 2) {
    // V: transpose to [e][m] (stride 136), store 8-consecutive-token chunks
    for (int hf = 0; hf < 2; ++hf) {
      if ((wid >> 2) == hf) {
#pragma unroll
        for (int i = 0; i < 8; ++i)
#pragma unroll
          for (int j = 0; j < 4; ++j) {
            half4h hv;
#pragma unroll
            for (int r = 0; r < 4; ++r) hv[r] = (_Float16)acc[i][j][r];
            *(half4h*)(smem + (wn + j * 16 + l15) * 136 + i * 16 + quad * 4) = hv;
          }
      }
      __syncthreads();
#pragma unroll
      for (int z = 0; z < 8; ++z) {
        const int c = tid + z * 512;
        const int e = c >> 4, mc = c & 15;
        const half8 vv = *(const half8*)(smem + e * 136 + mc * 8);
        const int rg = row0 + hf * 128 + mc * 8;
        const int b = rg / Nn, n = rg % Nn;
        const int eg = eb + e;
        const int hh = eg >> 6, d = eg & 63;
        *(half8*)(V8 + (((size_t)(b * Hh + hh) * NC + (n >> 3)) * 64 + d) * 8) = vv;
      }
      __syncthreads();
    }
  } else {
    // Q/K: [m][e] (stride 264), store 8-consecutive-d chunks per token
    _Float16* Ob = (tsel == 0) ? Q8 : K8;
    for (int hf = 0; hf < 2; ++hf) {
      if ((wid >> 2) == hf) {
#pragma unroll
        for (int i = 0; i < 8; ++i)
#pragma unroll
          for (int j = 0; j < 4; ++j)
#pragma unroll
            for (int r = 0; r < 4; ++r)
              smem[(i * 16 + quad * 4 + r) * 264 + wn + j * 16 + l15] =
                  (_Float16)acc[i][j][r];
      }
      __syncthreads();
#pragma unroll
      for (int z = 0; z < 8; ++z) {
        const int c = tid + z * 512;
        const int m = c >> 5, ec = c & 31;
        const half8 vv = *(const half8*)(smem + m * 264 + ec * 8);
        const int rg = row0 + hf * 128 + m;
        const int b = rg / Nn, n = rg % Nn;
        const int eg = eb + ec * 8;
        const int hh = eg >> 6, dc = (eg >> 3) & 7;
        *(half8*)(Ob + (((size_t)(b * Hh + hh) * 8 + dc) * Nn + n) * 8) = vv;
      }
      __syncthreads();
    }
  }
}

// ---------------------------------------------------------------- proj GEMM
// R0 body + bijective XCD swizzle (unchanged this round for attribution).
__global__ __launch_bounds__(256) void gemm_proj(const _Float16* __restrict__ Wbuf,
                                                 const _Float16* __restrict__ Wp,
                                                 const float* __restrict__ bias,
                                                 float* __restrict__ Out) {
  __shared__ __align__(16) _Float16 smem[128 * 64];
  _Float16* As = smem;
  _Float16* Bs = smem + 128 * 32;
  const int tid = threadIdx.x;
  const int lane = tid & 63, wid = tid >> 6;
  const int l15 = lane & 15, quad = lane >> 4;
  const int L = blockIdx.x;
  const int v = (L & 7) * 147 + (L >> 3);
  const int bx = v % 6, by = v / 6;
  const int row0 = by * 128;
  const int e0 = bx * 128;
  const int wm = (wid >> 1) * 64, wn = (wid & 1) * 64;

  const _Float16* Ag = Wbuf + (size_t)row0 * Dd;
  const _Float16* Bg = Wp + (size_t)e0 * Dd;

  f32x4 acc[4][4];
#pragma unroll
  for (int i = 0; i < 4; ++i)
#pragma unroll
    for (int j = 0; j < 4; ++j) acc[i][j] = (f32x4)0.0f;

  const int c0 = tid, c1 = tid + 256;
  const int r0s = c0 >> 2, o0 = ((c0 & 3) ^ ((r0s >> 1) & 3)) * 8;
  const int r1s = c1 >> 2, o1 = ((c1 & 3) ^ ((r1s >> 1) & 3)) * 8;
  const int csel = ((quad ^ ((l15 >> 1) & 3))) * 8;

  for (int kt = 0; kt < 24; ++kt) {
    const int k0 = kt * 32;
    __syncthreads();
    gll16(Ag + (size_t)r0s * Dd + k0 + o0, As + c0 * 8);
    gll16(Bg + (size_t)r0s * Dd + k0 + o0, Bs + c0 * 8);
    gll16(Ag + (size_t)r1s * Dd + k0 + o1, As + c1 * 8);
    gll16(Bg + (size_t)r1s * Dd + k0 + o1, Bs + c1 * 8);
    __syncthreads();
    half8 af[4], bf[4];
#pragma unroll
    for (int t = 0; t < 4; ++t) {
      af[t] = *(const half8*)(As + (wm + t * 16 + l15) * 32 + csel);
      bf[t] = *(const half8*)(Bs + (wn + t * 16 + l15) * 32 + csel);
    }
#pragma unroll
    for (int i = 0; i < 4; ++i)
#pragma unroll
      for (int j = 0; j < 4; ++j) acc[i][j] = MFMA(af[i], bf[j], acc[i][j]);
  }

#pragma unroll
  for (int j = 0; j < 4; ++j) {
    const int e = e0 + wn + j * 16 + l15;
    const float bj = bias[e];
#pragma unroll
    for (int i = 0; i < 4; ++i) {
      const int rb = row0 + wm + i * 16 + quad * 4;
#pragma unroll
      for (int r = 0; r < 4; ++r)
        Out[(size_t)(rb + r) * Dd + e] = acc[i][j][r] + bj;
    }
  }
}

// ------------------------------------------------------------ spatial attn
__global__ __launch_bounds__(256) void attn_spatial(const _Float16* __restrict__ Q8,
                                                    const _Float16* __restrict__ K8,
                                                    const _Float16* __restrict__ V8,
                                                    _Float16* __restrict__ Wbuf) {
  __shared__ __align__(16) _Float16 Vs[64 * 216];       // 27648 B
  __shared__ __align__(16) _Float16 Plds[4][16 * 232];  // 29696 B
  const int tid = threadIdx.x;
  const int lane = tid & 63, wid = tid >> 6;
  const int l15 = lane & 15, quad = lane >> 4;
  const int gid = blockIdx.x;
  const int h = gid % 6, f = (gid / 6) % Ff, b = gid / 96;
  const size_t bh = (size_t)b * Hh + h;
  const int g0 = f * Pp;
  const int off = g0 & 7;
  const int nc0 = g0 >> 3;
  const _Float16* Qp = Q8 + bh * 8 * (size_t)Nn * 8;
  const _Float16* Kp = K8 + bh * 8 * (size_t)Nn * 8;

  for (int c = tid; c < 26 * 64; c += 256) {
    const int d = c & 63, ncl = c >> 6;
    const half8 v = *(const half8*)(V8 + ((bh * NC + nc0 + ncl) * 64 + d) * 8);
    _Float16* dst = Vs + d * 216 + (8 - off) + ncl * 8;
    half4h lo, hi;
#pragma unroll
    for (int z = 0; z < 4; ++z) { lo[z] = v[z]; hi[z] = v[4 + z]; }
    *(half4h*)dst = lo;
    *(half4h*)(dst + 4) = hi;
  }
  _Float16* Pw = &Plds[wid][0];
  if (quad < 3) {  // zero P cols 208..231 (PV reads k up to 223)
    half8 z8;
#pragma unroll
    for (int z = 0; z < 8; ++z) z8[z] = (_Float16)0.0f;
    *(half8*)(Pw + l15 * 232 + 208 + quad * 8) = z8;
  }
  __syncthreads();

  half8 h8z;
#pragma unroll
  for (int z = 0; z < 8; ++z) h8z[z] = (_Float16)0.0f;

  for (int it = 0; it < 4; ++it) {
    const int qi = wid + it * 4;
    if (qi > 12) continue;
    const int qr = qi * 16 + l15;
    const int qtok = g0 + (qr < 195 ? qr : 195);
    const half8 bq0 = *(const half8*)(Qp + ((size_t)quad * Nn + qtok) * 8);
    const half8 bq1 = *(const half8*)(Qp + ((size_t)(quad + 4) * Nn + qtok) * 8);

    f32x4 ex[13];
    float rs = 0.0f;
#pragma unroll
    for (int kt = 0; kt < 13; ++kt) {
      const int krr = kt * 16 + l15;
      const int ktok = g0 + (krr < 195 ? krr : 195);
      const half8 ak0 = *(const half8*)(Kp + ((size_t)quad * Nn + ktok) * 8);
      const half8 ak1 = *(const half8*)(Kp + ((size_t)(quad + 4) * Nn + ktok) * 8);
      f32x4 t = (f32x4)0.0f;
      t = MFMA(ak0, bq0, t);
      t = MFMA(ak1, bq1, t);
      f32x4 e;
#pragma unroll
      for (int r = 0; r < 4; ++r) e[r] = __expf(t[r] * 0.125f);
      if (kt == 12 && quad >= 1) e = (f32x4)0.0f;  // keys 196..207
      ex[kt] = e;
      rs += e[0] + e[1] + e[2] + e[3];
    }
#pragma unroll
    for (int kt = 0; kt < 13; ++kt)
#pragma unroll
      for (int r = 0; r < 4; ++r)
        Pw[l15 * 232 + kt * 16 + quad * 4 + r] = (_Float16)ex[kt][r];
    rs += __shfl_xor(rs, 16);
    rs += __shfl_xor(rs, 32);
    lds_fence();

    f32x4 acc[4];
#pragma unroll
    for (int mt = 0; mt < 4; ++mt) acc[mt] = (f32x4)0.0f;
#pragma unroll
    for (int c = 0; c < 7; ++c) {
      const half8 bp = *(const half8*)(Pw + l15 * 232 + c * 32 + quad * 8);
      const int k0 = c * 32 + quad * 8;
#pragma unroll
      for (int mt = 0; mt < 4; ++mt) {
        const int d = mt * 16 + l15;
        half8 av = h8z;
        if (k0 < 196) av = *(const half8*)(Vs + d * 216 + 8 + k0);
        acc[mt] = MFMA(av, bp, acc[mt]);  // O^T[d][q]
      }
    }
    const float inv = 1.0f / rs;
    if (qr < 196) {
      _Float16* base = Wbuf + (size_t)(b * Nn + g0 + qr) * Dd + h * HD;
#pragma unroll
      for (int mt = 0; mt < 4; ++mt) {
        half4h o;
#pragma unroll
        for (int r = 0; r < 4; ++r) o[r] = (_Float16)(acc[mt][r] * inv);
        *(half4h*)(base + mt * 16 + quad * 4) = o;
      }
    }
    __builtin_amdgcn_sched_barrier(0);
  }
}

// ----------------------------------------------------------- temporal attn
__global__ __launch_bounds__(256) void attn_temporal(const _Float16* __restrict__ Q8,
                                                     const _Float16* __restrict__ K8,
                                                     const _Float16* __restrict__ V8,
                                                     _Float16* __restrict__ Wbuf) {
  __shared__ __align__(16) _Float16 Plds[4][16 * 40];
  const int tid = threadIdx.x;
  const int lane = tid & 63, wid = tid >> 6;
  const int l15 = lane & 15, quad = lane >> 4;
  const int p = blockIdx.x * 4 + wid;
  const int J0 = p << 4;
  const int b = J0 / 18816;  // H2*N
  const int rem = J0 % 18816;
  const int hh = rem / Nn;
  const int n0 = rem % Nn;   // 16-aligned
  const size_t bh = (size_t)b * Hh + 6 + hh;
  const _Float16* Qp = Q8 + bh * 8 * (size_t)Nn * 8;
  const _Float16* Kp = K8 + bh * 8 * (size_t)Nn * 8;
  _Float16* Pw = &Plds[wid][0];

  const int tok = n0 + l15;
  const half8 bq0 = *(const half8*)(Qp + ((size_t)quad * Nn + tok) * 8);
  const half8 bq1 = *(const half8*)(Qp + ((size_t)(quad + 4) * Nn + tok) * 8);
  const half8 ak0 = *(const half8*)(Kp + ((size_t)quad * Nn + tok) * 8);
  const half8 ak1 = *(const half8*)(Kp + ((size_t)(quad + 4) * Nn + tok) * 8);
  f32x4 t = (f32x4)0.0f;
  t = MFMA(ak0, bq0, t);  // St[k][q]
  t = MFMA(ak1, bq1, t);
  f32x4 e;
#pragma unroll
  for (int r = 0; r < 4; ++r) e[r] = __expf(t[r] * 0.125f);
  float rs = e[0] + e[1] + e[2] + e[3];
  rs += __shfl_xor(rs, 16);
  rs += __shfl_xor(rs, 32);

#pragma unroll
  for (int r = 0; r < 4; ++r) Pw[l15 * 40 + quad * 4 + r] = (_Float16)e[r];
  {
    half4h z4;
    z4.x = z4.y = z4.z = z4.w = (_Float16)0.0f;
    *(half4h*)(Pw + l15 * 40 + 16 + quad * 4) = z4;  // zero k=16..31
  }
  lds_fence();

  const half8 bp = *(const half8*)(Pw + l15 * 40 + quad * 8);  // B: P[q][k]
  half8 h8z;
#pragma unroll
  for (int z = 0; z < 8; ++z) h8z[z] = (_Float16)0.0f;

  const float inv = 1.0f / rs;
  _Float16* base = Wbuf + (size_t)(b * Nn + n0 + l15) * Dd + (6 + hh) * HD;
#pragma unroll
  for (int mt = 0; mt < 4; ++mt) {
    const int d = mt * 16 + l15;
    half8 av = h8z;
    if (quad < 2)
      av = *(const half8*)(V8 + ((bh * NC + (n0 >> 3) + quad) * 64 + d) * 8);
    f32x4 acc = (f32x4)0.0f;
    acc = MFMA(av, bp, acc);  // O^T[d][q]
    half4h o;
#pragma unroll
    for (int r = 0; r < 4; ++r) o[r] = (_Float16)(acc[r] * inv);
    *(half4h*)(base + mt * 16 + quad * 4) = o;
  }
}

// ---------------------------------------------------------------- launcher
extern "C" void kernel_launch(void* const* d_in, const int* in_sizes, int n_in,
                              void* d_out, int out_size, void* d_ws, size_t ws_size,
                              hipStream_t stream) {
  const float* x = (const float*)d_in[0];
  const float* w_qkv = (const float*)d_in[1];
  const float* w_proj = (const float*)d_in[2];
  const float* b_proj = (const float*)d_in[3];
  float* out = (float*)d_out;

  _Float16* Xh = (_Float16*)d_ws;    // 19267584 elems; reused as Wbuf
  _Float16* Q8 = Xh + 19267584;      // (b,h,dc,n,8)
  _Float16* K8 = Q8 + 19267584;
  _Float16* V8 = K8 + 19267584;      // (b,h,n/8,d,8)
  _Float16* Wqh = V8 + 19267584;     // 1769472
  _Float16* Wph = Wqh + 1769472;     // 589824

  cvt_all<<<21120, 256, 0, stream>>>(x, w_qkv, w_proj, Xh, Wqh, Wph);
  gemm_qkv<<<882, 512, 0, stream>>>(Xh, Wqh, Q8, K8, V8);
  attn_spatial<<<768, 256, 0, stream>>>(Q8, K8, V8, Xh);
  attn_temporal<<<2352, 256, 0, stream>>>(Q8, K8, V8, Xh);
  gemm_proj<<<1176, 256, 0, stream>>>(Xh, Wph, b_proj, out);
}

// Round 5
// 332.062 us; speedup vs baseline: 1.1528x; 1.1528x over previous
//
#include <hip/hip_runtime.h>

#define DEV __device__ __forceinline__

typedef _Float16 half8  __attribute__((ext_vector_type(8)));
typedef _Float16 half4h __attribute__((ext_vector_type(4)));
typedef float    f32x4  __attribute__((ext_vector_type(4)));

static constexpr int Bb = 8;
static constexpr int Ff = 16;
static constexpr int Pp = 196;
static constexpr int Dd = 768;
static constexpr int Hh = 12;
static constexpr int HD = 64;
static constexpr int Nn = 3136;    // F*P tokens per batch
static constexpr int NC = 392;     // Nn/8 token chunks per batch

#define MFMA(a, b, c) __builtin_amdgcn_mfma_f32_16x16x32_f16(a, b, c, 0, 0, 0)

DEV void gll16(const _Float16* g, _Float16* l) {
  __builtin_amdgcn_global_load_lds(
      (__attribute__((address_space(1))) void*)(g),
      (__attribute__((address_space(3))) void*)(l), 16, 0, 0);
}

// LDS-only fence: wait DS ops, compiler memory barrier. Does NOT drain vmcnt,
// so global loads stay in flight across it.
DEV void lds_fence() { asm volatile("s_waitcnt lgkmcnt(0)" ::: "memory"); }

// ---------------------------------------------------------------- convert
__global__ __launch_bounds__(256) void cvt_all(const float* __restrict__ x,
                                               const float* __restrict__ wq,
                                               const float* __restrict__ wp,
                                               _Float16* __restrict__ xh,
                                               _Float16* __restrict__ wqh,
                                               _Float16* __restrict__ wph) {
  const int NX = 4816896, NQ = 442368;  // in f32x4 units
  int i = blockIdx.x * 256 + threadIdx.x;
  const float* s;
  _Float16* d;
  int j;
  if (i < NX) { s = x; d = xh; j = i; }
  else if (i < NX + NQ) { s = wq; d = wqh; j = i - NX; }
  else { s = wp; d = wph; j = i - NX - NQ; }
  f32x4 v = ((const f32x4*)s)[j];
  half4h h;
  h.x = (_Float16)v.x; h.y = (_Float16)v.y;
  h.z = (_Float16)v.z; h.w = (_Float16)v.w;
  ((half4h*)d)[j] = h;
}

// ---------------------------------------------------------------- QKV GEMM
// BM=128 x BN=256, 4 waves (2M x 2N), each wave owns 64x128 (af[4] x bf[8],
// 32 MFMA/K-step): 25% less LDS traffic per MFMA than the 64x64 scheme.
// Ring-3 LDS (3 x 24 KiB = 72 KiB -> 2 independent blocks/CU = 2 waves/SIMD
// from DIFFERENT blocks, preserving R3's unsynchronized overlap). Sync
// ledger identical to R3 (verified twice): tile t stages t+2 into slot
// (t+2)%3; reads slot t%3; one s_waitcnt vmcnt(6) lgkmcnt(0) + raw
// s_barrier per tile (vmcnt(6) retires exactly stage(t+1), stage(t+2)'s 6
// loads stay in flight; lgkm-retired reads before the barrier make the next
// tile's stage-issue safe). Epilogue: single-pass LDS transpose (fits ring).
__global__ __launch_bounds__(256, 2) void gemm_qkv(const _Float16* __restrict__ X,
                                                   const _Float16* __restrict__ W,
                                                   _Float16* __restrict__ Q8,
                                                   _Float16* __restrict__ K8,
                                                   _Float16* __restrict__ V8) {
  __shared__ __align__(16) _Float16 smem[3 * 12288];  // 72 KiB ring; epilogue reuses
  const int tid = threadIdx.x;
  const int lane = tid & 63, wid = tid >> 6;
  const int l15 = lane & 15, quad = lane >> 4;
  // bijective XCD-chunked swizzle (m204): 1764 = 8*220 + 4
  const int L = blockIdx.x;
  const int xcd = L & 7, idx = L >> 3;
  const int v = (xcd < 4 ? xcd * 221 : 884 + (xcd - 4) * 220) + idx;
  const int bx = v % 9, by = v / 9;
  const int row0 = by * 128;
  const int e0 = bx * 256;
  const int wm = (wid >> 1) * 64, wn = (wid & 1) * 128;

  const _Float16* Ag = X + (size_t)row0 * Dd;
  const _Float16* Bg = W + (size_t)e0 * Dd;

  f32x4 acc[4][8];
#pragma unroll
  for (int i = 0; i < 4; ++i)
#pragma unroll
    for (int j = 0; j < 8; ++j) acc[i][j] = (f32x4)0.0f;

  const int csel = (quad ^ ((l15 >> 1) & 3)) * 8;

  // stage: A rows 0..127 -> slot[0,4096), B rows 0..255 -> slot[4096,12288).
  // 6 chunk-loads per thread; dst linear (c*8), src carries the XOR swizzle.
  auto stage = [&](int t) {
    const int kn = t * 32;
    _Float16* base = smem + (t % 3) * 12288;
#pragma unroll
    for (int j = 0; j < 6; ++j) {
      const int c = tid + j * 256;
      const int r = c >> 2;
      const int o = ((c & 3) ^ ((r >> 1) & 3)) * 8;
      const _Float16* src = (j < 2) ? (Ag + (size_t)r * Dd + kn + o)
                                    : (Bg + (size_t)(r - 128) * Dd + kn + o);
      gll16(src, base + c * 8);
    }
  };

  // prologue: stage tiles 0,1; wait tile 0 only (tile 1's 6 loads in flight)
  stage(0);
  stage(1);
  asm volatile("s_waitcnt vmcnt(6)" ::: "memory");
  asm volatile("s_barrier" ::: "memory");

  auto tile = [&](int T, int SL, bool STG, int WV) {
    if (STG) stage(T + 2);
    const _Float16* As_ = smem + SL * 12288;
    const _Float16* Bs_ = As_ + 4096;
    half8 af[4], bf[8];
#pragma unroll
    for (int m = 0; m < 4; ++m)
      af[m] = *(const half8*)(As_ + (wm + m * 16 + l15) * 32 + csel);
#pragma unroll
    for (int n = 0; n < 8; ++n)
      bf[n] = *(const half8*)(Bs_ + (wn + n * 16 + l15) * 32 + csel);
    if (WV == 6)      asm volatile("s_waitcnt vmcnt(6) lgkmcnt(0)" ::: "memory");
    else if (WV == 0) asm volatile("s_waitcnt vmcnt(0) lgkmcnt(0)" ::: "memory");
    else              asm volatile("s_waitcnt lgkmcnt(0)" ::: "memory");
    asm volatile("s_barrier" ::: "memory");
    __builtin_amdgcn_s_setprio(1);
#pragma unroll
    for (int m = 0; m < 4; ++m)
#pragma unroll
      for (int n = 0; n < 8; ++n) acc[m][n] = MFMA(af[m], bf[n], acc[m][n]);
    __builtin_amdgcn_s_setprio(0);
  };

#pragma unroll
  for (int g = 0; g < 8; ++g) {
    const int T = 3 * g;
    tile(T,     0, T < 22,     (T < 22) ? 6 : 0);
    tile(T + 1, 1, T + 1 < 22, (T + 1 < 22) ? 6 : ((T + 1 == 22) ? 0 : -1));
    tile(T + 2, 2, T + 2 < 22, (T + 2 < 22) ? 6 : ((T + 2 == 22) ? 0 : -1));
  }

  // -------- epilogue: single-pass LDS transpose (72 KiB ring reused)
  __syncthreads();
  const int tsel = bx / 3;             // 0=Q, 1=K, 2=V
  const int eb = e0 - tsel * Dd;       // 0/256/512 within the matrix
  if (tsel == 2) {
    // V: [e][m] stride 132 (69.6 KiB), store 8-consecutive-token chunks
#pragma unroll
    for (int i = 0; i < 4; ++i)
#pragma unroll
      for (int j = 0; j < 8; ++j) {
        half4h hv;
#pragma unroll
        for (int r = 0; r < 4; ++r) hv[r] = (_Float16)acc[i][j][r];
        *(half4h*)(smem + (wn + j * 16 + l15) * 132 + wm + i * 16 + quad * 4) = hv;
      }
    __syncthreads();
#pragma unroll
    for (int z = 0; z < 16; ++z) {
      const int c = tid + z * 256;
      const int e = c >> 4, mc = c & 15;
      const half8 vv = *(const half8*)(smem + e * 132 + mc * 8);
      const int rg = row0 + mc * 8;
      const int b = rg / Nn, n = rg % Nn;
      const int em = eb + e;
      const int hh = em >> 6, d = em & 63;
      *(half8*)(V8 + (((size_t)(b * Hh + hh) * NC + (n >> 3)) * 64 + d) * 8) = vv;
    }
  } else {
    // Q/K: [m][e] stride 264 (67.6 KiB), store 8-consecutive-d chunks
    _Float16* Ob = (tsel == 0) ? Q8 : K8;
#pragma unroll
    for (int i = 0; i < 4; ++i)
#pragma unroll
      for (int j = 0; j < 8; ++j)
#pragma unroll
        for (int r = 0; r < 4; ++r)
          smem[(wm + i * 16 + quad * 4 + r) * 264 + wn + j * 16 + l15] =
              (_Float16)acc[i][j][r];
    __syncthreads();
#pragma unroll
    for (int z = 0; z < 16; ++z) {
      const int c = tid + z * 256;
      const int ec = c >> 7, m = c & 127;
      const half8 vv = *(const half8*)(smem + m * 264 + ec * 8);
      const int rg = row0 + m;
      const int b = rg / Nn, n = rg % Nn;
      const int em = eb + ec * 8;
      const int hh = em >> 6, dc = (em >> 3) & 7;
      *(half8*)(Ob + (((size_t)(b * Hh + hh) * 8 + dc) * Nn + n) * 8) = vv;
    }
  }
}

// ---------------------------------------------------------------- proj GEMM
// Same BM=128 x BN=256 ring-3 structure; trivial f32+bias epilogue.
// Grid 588 = 8*73 + 4 (m204 bijective swizzle).
__global__ __launch_bounds__(256, 2) void gemm_proj(const _Float16* __restrict__ Wbuf,
                                                    const _Float16* __restrict__ Wp,
                                                    const float* __restrict__ bias,
                                                    float* __restrict__ Out) {
  __shared__ __align__(16) _Float16 smem[3 * 12288];
  const int tid = threadIdx.x;
  const int lane = tid & 63, wid = tid >> 6;
  const int l15 = lane & 15, quad = lane >> 4;
  const int L = blockIdx.x;
  const int xcd = L & 7, idx = L >> 3;
  const int v = (xcd < 4 ? xcd * 74 : 296 + (xcd - 4) * 73) + idx;
  const int bx = v % 3, by = v / 3;
  const int row0 = by * 128;
  const int e0 = bx * 256;
  const int wm = (wid >> 1) * 64, wn = (wid & 1) * 128;

  const _Float16* Ag = Wbuf + (size_t)row0 * Dd;
  const _Float16* Bg = Wp + (size_t)e0 * Dd;

  f32x4 acc[4][8];
#pragma unroll
  for (int i = 0; i < 4; ++i)
#pragma unroll
    for (int j = 0; j < 8; ++j) acc[i][j] = (f32x4)0.0f;

  const int csel = (quad ^ ((l15 >> 1) & 3)) * 8;

  auto stage = [&](int t) {
    const int kn = t * 32;
    _Float16* base = smem + (t % 3) * 12288;
#pragma unroll
    for (int j = 0; j < 6; ++j) {
      const int c = tid + j * 256;
      const int r = c >> 2;
      const int o = ((c & 3) ^ ((r >> 1) & 3)) * 8;
      const _Float16* src = (j < 2) ? (Ag + (size_t)r * Dd + kn + o)
                                    : (Bg + (size_t)(r - 128) * Dd + kn + o);
      gll16(src, base + c * 8);
    }
  };

  stage(0);
  stage(1);
  asm volatile("s_waitcnt vmcnt(6)" ::: "memory");
  asm volatile("s_barrier" ::: "memory");

  auto tile = [&](int T, int SL, bool STG, int WV) {
    if (STG) stage(T + 2);
    const _Float16* As_ = smem + SL * 12288;
    const _Float16* Bs_ = As_ + 4096;
    half8 af[4], bf[8];
#pragma unroll
    for (int m = 0; m < 4; ++m)
      af[m] = *(const half8*)(As_ + (wm + m * 16 + l15) * 32 + csel);
#pragma unroll
    for (int n = 0; n < 8; ++n)
      bf[n] = *(const half8*)(Bs_ + (wn + n * 16 + l15) * 32 + csel);
    if (WV == 6)      asm volatile("s_waitcnt vmcnt(6) lgkmcnt(0)" ::: "memory");
    else if (WV == 0) asm volatile("s_waitcnt vmcnt(0) lgkmcnt(0)" ::: "memory");
    else              asm volatile("s_waitcnt lgkmcnt(0)" ::: "memory");
    asm volatile("s_barrier" ::: "memory");
    __builtin_amdgcn_s_setprio(1);
#pragma unroll
    for (int m = 0; m < 4; ++m)
#pragma unroll
      for (int n = 0; n < 8; ++n) acc[m][n] = MFMA(af[m], bf[n], acc[m][n]);
    __builtin_amdgcn_s_setprio(0);
  };

#pragma unroll
  for (int g = 0; g < 8; ++g) {
    const int T = 3 * g;
    tile(T,     0, T < 22,     (T < 22) ? 6 : 0);
    tile(T + 1, 1, T + 1 < 22, (T + 1 < 22) ? 6 : ((T + 1 == 22) ? 0 : -1));
    tile(T + 2, 2, T + 2 < 22, (T + 2 < 22) ? 6 : ((T + 2 == 22) ? 0 : -1));
  }

#pragma unroll
  for (int j = 0; j < 8; ++j) {
    const int e = e0 + wn + j * 16 + l15;
    const float bj = bias[e];
#pragma unroll
    for (int i = 0; i < 4; ++i) {
      const int rb = row0 + wm + i * 16 + quad * 4;
#pragma unroll
      for (int r = 0; r < 4; ++r)
        Out[(size_t)(rb + r) * Dd + e] = acc[i][j][r] + bj;
    }
  }
}

// ------------------------------------------------------------ spatial attn
__global__ __launch_bounds__(256) void attn_spatial(const _Float16* __restrict__ Q8,
                                                    const _Float16* __restrict__ K8,
                                                    const _Float16* __restrict__ V8,
                                                    _Float16* __restrict__ Wbuf) {
  __shared__ __align__(16) _Float16 Vs[64 * 216];       // 27648 B
  __shared__ __align__(16) _Float16 Plds[4][16 * 232];  // 29696 B
  const int tid = threadIdx.x;
  const int lane = tid & 63, wid = tid >> 6;
  const int l15 = lane & 15, quad = lane >> 4;
  const int gid = blockIdx.x;
  const int h = gid % 6, f = (gid / 6) % Ff, b = gid / 96;
  const size_t bh = (size_t)b * Hh + h;
  const int g0 = f * Pp;
  const int off = g0 & 7;
  const int nc0 = g0 >> 3;
  const _Float16* Qp = Q8 + bh * 8 * (size_t)Nn * 8;
  const _Float16* Kp = K8 + bh * 8 * (size_t)Nn * 8;

  for (int c = tid; c < 26 * 64; c += 256) {
    const int d = c & 63, ncl = c >> 6;
    const half8 v = *(const half8*)(V8 + ((bh * NC + nc0 + ncl) * 64 + d) * 8);
    _Float16* dst = Vs + d * 216 + (8 - off) + ncl * 8;
    half4h lo, hi;
#pragma unroll
    for (int z = 0; z < 4; ++z) { lo[z] = v[z]; hi[z] = v[4 + z]; }
    *(half4h*)dst = lo;
    *(half4h*)(dst + 4) = hi;
  }
  _Float16* Pw = &Plds[wid][0];
  if (quad < 3) {  // zero P cols 208..231 (PV reads k up to 223)
    half8 z8;
#pragma unroll
    for (int z = 0; z < 8; ++z) z8[z] = (_Float16)0.0f;
    *(half8*)(Pw + l15 * 232 + 208 + quad * 8) = z8;
  }
  __syncthreads();

  half8 h8z;
#pragma unroll
  for (int z = 0; z < 8; ++z) h8z[z] = (_Float16)0.0f;

  for (int it = 0; it < 4; ++it) {
    const int qi = wid + it * 4;
    if (qi > 12) continue;
    const int qr = qi * 16 + l15;
    const int qtok = g0 + (qr < 195 ? qr : 195);
    const half8 bq0 = *(const half8*)(Qp + ((size_t)quad * Nn + qtok) * 8);
    const half8 bq1 = *(const half8*)(Qp + ((size_t)(quad + 4) * Nn + qtok) * 8);

    f32x4 ex[13];
    float rs = 0.0f;
#pragma unroll
    for (int kt = 0; kt < 13; ++kt) {
      const int krr = kt * 16 + l15;
      const int ktok = g0 + (krr < 195 ? krr : 195);
      const half8 ak0 = *(const half8*)(Kp + ((size_t)quad * Nn + ktok) * 8);
      const half8 ak1 = *(const half8*)(Kp + ((size_t)(quad + 4) * Nn + ktok) * 8);
      f32x4 t = (f32x4)0.0f;
      t = MFMA(ak0, bq0, t);
      t = MFMA(ak1, bq1, t);
      f32x4 e;
#pragma unroll
      for (int r = 0; r < 4; ++r) e[r] = __expf(t[r] * 0.125f);
      if (kt == 12 && quad >= 1) e = (f32x4)0.0f;  // keys 196..207
      ex[kt] = e;
      rs += e[0] + e[1] + e[2] + e[3];
    }
#pragma unroll
    for (int kt = 0; kt < 13; ++kt)
#pragma unroll
      for (int r = 0; r < 4; ++r)
        Pw[l15 * 232 + kt * 16 + quad * 4 + r] = (_Float16)ex[kt][r];
    rs += __shfl_xor(rs, 16);
    rs += __shfl_xor(rs, 32);
    lds_fence();

    f32x4 acc[4];
#pragma unroll
    for (int mt = 0; mt < 4; ++mt) acc[mt] = (f32x4)0.0f;
#pragma unroll
    for (int c = 0; c < 7; ++c) {
      const half8 bp = *(const half8*)(Pw + l15 * 232 + c * 32 + quad * 8);
      const int k0 = c * 32 + quad * 8;
#pragma unroll
      for (int mt = 0; mt < 4; ++mt) {
        const int d = mt * 16 + l15;
        half8 av = h8z;
        if (k0 < 196) av = *(const half8*)(Vs + d * 216 + 8 + k0);
        acc[mt] = MFMA(av, bp, acc[mt]);  // O^T[d][q]
      }
    }
    const float inv = 1.0f / rs;
    if (qr < 196) {
      _Float16* base = Wbuf + (size_t)(b * Nn + g0 + qr) * Dd + h * HD;
#pragma unroll
      for (int mt = 0; mt < 4; ++mt) {
        half4h o;
#pragma unroll
        for (int r = 0; r < 4; ++r) o[r] = (_Float16)(acc[mt][r] * inv);
        *(half4h*)(base + mt * 16 + quad * 4) = o;
      }
    }
    __builtin_amdgcn_sched_barrier(0);
  }
}

// ----------------------------------------------------------- temporal attn
__global__ __launch_bounds__(256) void attn_temporal(const _Float16* __restrict__ Q8,
                                                     const _Float16* __restrict__ K8,
                                                     const _Float16* __restrict__ V8,
                                                     _Float16* __restrict__ Wbuf) {
  __shared__ __align__(16) _Float16 Plds[4][16 * 40];
  const int tid = threadIdx.x;
  const int lane = tid & 63, wid = tid >> 6;
  const int l15 = lane & 15, quad = lane >> 4;
  const int p = blockIdx.x * 4 + wid;
  const int J0 = p << 4;
  const int b = J0 / 18816;  // H2*N
  const int rem = J0 % 18816;
  const int hh = rem / Nn;
  const int n0 = rem % Nn;   // 16-aligned
  const size_t bh = (size_t)b * Hh + 6 + hh;
  const _Float16* Qp = Q8 + bh * 8 * (size_t)Nn * 8;
  const _Float16* Kp = K8 + bh * 8 * (size_t)Nn * 8;
  _Float16* Pw = &Plds[wid][0];

  const int tok = n0 + l15;
  const half8 bq0 = *(const half8*)(Qp + ((size_t)quad * Nn + tok) * 8);
  const half8 bq1 = *(const half8*)(Qp + ((size_t)(quad + 4) * Nn + tok) * 8);
  const half8 ak0 = *(const half8*)(Kp + ((size_t)quad * Nn + tok) * 8);
  const half8 ak1 = *(const half8*)(Kp + ((size_t)(quad + 4) * Nn + tok) * 8);
  f32x4 t = (f32x4)0.0f;
  t = MFMA(ak0, bq0, t);  // St[k][q]
  t = MFMA(ak1, bq1, t);
  f32x4 e;
#pragma unroll
  for (int r = 0; r < 4; ++r) e[r] = __expf(t[r] * 0.125f);
  float rs = e[0] + e[1] + e[2] + e[3];
  rs += __shfl_xor(rs, 16);
  rs += __shfl_xor(rs, 32);

#pragma unroll
  for (int r = 0; r < 4; ++r) Pw[l15 * 40 + quad * 4 + r] = (_Float16)e[r];
  {
    half4h z4;
    z4.x = z4.y = z4.z = z4.w = (_Float16)0.0f;
    *(half4h*)(Pw + l15 * 40 + 16 + quad * 4) = z4;  // zero k=16..31
  }
  lds_fence();

  const half8 bp = *(const half8*)(Pw + l15 * 40 + quad * 8);  // B: P[q][k]
  half8 h8z;
#pragma unroll
  for (int z = 0; z < 8; ++z) h8z[z] = (_Float16)0.0f;

  const float inv = 1.0f / rs;
  _Float16* base = Wbuf + (size_t)(b * Nn + n0 + l15) * Dd + (6 + hh) * HD;
#pragma unroll
  for (int mt = 0; mt < 4; ++mt) {
    const int d = mt * 16 + l15;
    half8 av = h8z;
    if (quad < 2)
      av = *(const half8*)(V8 + ((bh * NC + (n0 >> 3) + quad) * 64 + d) * 8);
    f32x4 acc = (f32x4)0.0f;
    acc = MFMA(av, bp, acc);  // O^T[d][q]
    half4h o;
#pragma unroll
    for (int r = 0; r < 4; ++r) o[r] = (_Float16)(acc[r] * inv);
    *(half4h*)(base + mt * 16 + quad * 4) = o;
  }
}

// ---------------------------------------------------------------- launcher
extern "C" void kernel_launch(void* const* d_in, const int* in_sizes, int n_in,
                              void* d_out, int out_size, void* d_ws, size_t ws_size,
                              hipStream_t stream) {
  const float* x = (const float*)d_in[0];
  const float* w_qkv = (const float*)d_in[1];
  const float* w_proj = (const float*)d_in[2];
  const float* b_proj = (const float*)d_in[3];
  float* out = (float*)d_out;

  _Float16* Xh = (_Float16*)d_ws;    // 19267584 elems; reused as Wbuf
  _Float16* Q8 = Xh + 19267584;      // (b,h,dc,n,8)
  _Float16* K8 = Q8 + 19267584;
  _Float16* V8 = K8 + 19267584;      // (b,h,n/8,d,8)
  _Float16* Wqh = V8 + 19267584;     // 1769472
  _Float16* Wph = Wqh + 1769472;     // 589824

  cvt_all<<<21120, 256, 0, stream>>>(x, w_qkv, w_proj, Xh, Wqh, Wph);
  gemm_qkv<<<1764, 256, 0, stream>>>(Xh, Wqh, Q8, K8, V8);
  attn_spatial<<<768, 256, 0, stream>>>(Q8, K8, V8, Xh);
  attn_temporal<<<2352, 256, 0, stream>>>(Q8, K8, V8, Xh);
  gemm_proj<<<588, 256, 0, stream>>>(Xh, Wph, b_proj, out);
}

// Round 6
// 327.416 us; speedup vs baseline: 1.1691x; 1.0142x over previous
//
#include <hip/hip_runtime.h>

#define DEV __device__ __forceinline__

typedef _Float16 half8  __attribute__((ext_vector_type(8)));
typedef _Float16 half4h __attribute__((ext_vector_type(4)));
typedef float    f32x4  __attribute__((ext_vector_type(4)));

static constexpr int Bb = 8;
static constexpr int Ff = 16;
static constexpr int Pp = 196;
static constexpr int Dd = 768;
static constexpr int Hh = 12;
static constexpr int HD = 64;
static constexpr int Nn = 3136;    // F*P tokens per batch
static constexpr int NC = 392;     // Nn/8 token chunks per batch

#define MFMA(a, b, c) __builtin_amdgcn_mfma_f32_16x16x32_f16(a, b, c, 0, 0, 0)

DEV void gll16(const _Float16* g, _Float16* l) {
  __builtin_amdgcn_global_load_lds(
      (__attribute__((address_space(1))) void*)(g),
      (__attribute__((address_space(3))) void*)(l), 16, 0, 0);
}

// LDS-only fence: wait DS ops, compiler memory barrier. Does NOT drain vmcnt,
// so global loads stay in flight across it.
DEV void lds_fence() { asm volatile("s_waitcnt lgkmcnt(0)" ::: "memory"); }

// ---------------------------------------------------------------- convert
__global__ __launch_bounds__(256) void cvt_all(const float* __restrict__ x,
                                               const float* __restrict__ wq,
                                               const float* __restrict__ wp,
                                               _Float16* __restrict__ xh,
                                               _Float16* __restrict__ wqh,
                                               _Float16* __restrict__ wph) {
  const int NX = 4816896, NQ = 442368;  // in f32x4 units
  int i = blockIdx.x * 256 + threadIdx.x;
  const float* s;
  _Float16* d;
  int j;
  if (i < NX) { s = x; d = xh; j = i; }
  else if (i < NX + NQ) { s = wq; d = wqh; j = i - NX; }
  else { s = wp; d = wph; j = i - NX - NQ; }
  f32x4 v = ((const f32x4*)s)[j];
  half4h h;
  h.x = (_Float16)v.x; h.y = (_Float16)v.y;
  h.z = (_Float16)v.z; h.w = (_Float16)v.w;
  ((half4h*)d)[j] = h;
}

// ---------------------------------------------------------------- QKV GEMM
// BM=128 x BN=256, 4 waves (2M x 2N), each wave owns 64x128 (af[4] x bf[8],
// 32 MFMA/K-step). Ring-3 LDS (3 x 24 KiB = 72 KiB -> 2 independent
// blocks/CU = 2 waves/SIMD from DIFFERENT blocks). Sync ledger: tile t
// stages t+2 into slot (t+2)%3; reads slot t%3; one s_waitcnt vmcnt(6)
// lgkmcnt(0) + raw s_barrier per tile. (R5-verified: 106 us, MfmaUtil 36.)
__global__ __launch_bounds__(256, 2) void gemm_qkv(const _Float16* __restrict__ X,
                                                   const _Float16* __restrict__ W,
                                                   _Float16* __restrict__ Q8,
                                                   _Float16* __restrict__ K8,
                                                   _Float16* __restrict__ V8) {
  __shared__ __align__(16) _Float16 smem[3 * 12288];  // 72 KiB ring; epilogue reuses
  const int tid = threadIdx.x;
  const int lane = tid & 63, wid = tid >> 6;
  const int l15 = lane & 15, quad = lane >> 4;
  // bijective XCD-chunked swizzle (m204): 1764 = 8*220 + 4
  const int L = blockIdx.x;
  const int xcd = L & 7, idx = L >> 3;
  const int v = (xcd < 4 ? xcd * 221 : 884 + (xcd - 4) * 220) + idx;
  const int bx = v % 9, by = v / 9;
  const int row0 = by * 128;
  const int e0 = bx * 256;
  const int wm = (wid >> 1) * 64, wn = (wid & 1) * 128;

  const _Float16* Ag = X + (size_t)row0 * Dd;
  const _Float16* Bg = W + (size_t)e0 * Dd;

  f32x4 acc[4][8];
#pragma unroll
  for (int i = 0; i < 4; ++i)
#pragma unroll
    for (int j = 0; j < 8; ++j) acc[i][j] = (f32x4)0.0f;

  const int csel = (quad ^ ((l15 >> 1) & 3)) * 8;

  auto stage = [&](int t) {
    const int kn = t * 32;
    _Float16* base = smem + (t % 3) * 12288;
#pragma unroll
    for (int j = 0; j < 6; ++j) {
      const int c = tid + j * 256;
      const int r = c >> 2;
      const int o = ((c & 3) ^ ((r >> 1) & 3)) * 8;
      const _Float16* src = (j < 2) ? (Ag + (size_t)r * Dd + kn + o)
                                    : (Bg + (size_t)(r - 128) * Dd + kn + o);
      gll16(src, base + c * 8);
    }
  };

  stage(0);
  stage(1);
  asm volatile("s_waitcnt vmcnt(6)" ::: "memory");
  asm volatile("s_barrier" ::: "memory");

  auto tile = [&](int T, int SL, bool STG, int WV) {
    if (STG) stage(T + 2);
    const _Float16* As_ = smem + SL * 12288;
    const _Float16* Bs_ = As_ + 4096;
    half8 af[4], bf[8];
#pragma unroll
    for (int m = 0; m < 4; ++m)
      af[m] = *(const half8*)(As_ + (wm + m * 16 + l15) * 32 + csel);
#pragma unroll
    for (int n = 0; n < 8; ++n)
      bf[n] = *(const half8*)(Bs_ + (wn + n * 16 + l15) * 32 + csel);
    if (WV == 6)      asm volatile("s_waitcnt vmcnt(6) lgkmcnt(0)" ::: "memory");
    else if (WV == 0) asm volatile("s_waitcnt vmcnt(0) lgkmcnt(0)" ::: "memory");
    else              asm volatile("s_waitcnt lgkmcnt(0)" ::: "memory");
    asm volatile("s_barrier" ::: "memory");
    __builtin_amdgcn_s_setprio(1);
#pragma unroll
    for (int m = 0; m < 4; ++m)
#pragma unroll
      for (int n = 0; n < 8; ++n) acc[m][n] = MFMA(af[m], bf[n], acc[m][n]);
    __builtin_amdgcn_s_setprio(0);
  };

#pragma unroll
  for (int g = 0; g < 8; ++g) {
    const int T = 3 * g;
    tile(T,     0, T < 22,     (T < 22) ? 6 : 0);
    tile(T + 1, 1, T + 1 < 22, (T + 1 < 22) ? 6 : ((T + 1 == 22) ? 0 : -1));
    tile(T + 2, 2, T + 2 < 22, (T + 2 < 22) ? 6 : ((T + 2 == 22) ? 0 : -1));
  }

  // -------- epilogue: single-pass LDS transpose (72 KiB ring reused)
  __syncthreads();
  const int tsel = bx / 3;             // 0=Q, 1=K, 2=V
  const int eb = e0 - tsel * Dd;       // 0/256/512 within the matrix
  if (tsel == 2) {
    // V: [e][m] stride 132, store 8-consecutive-token chunks
#pragma unroll
    for (int i = 0; i < 4; ++i)
#pragma unroll
      for (int j = 0; j < 8; ++j) {
        half4h hv;
#pragma unroll
        for (int r = 0; r < 4; ++r) hv[r] = (_Float16)acc[i][j][r];
        *(half4h*)(smem + (wn + j * 16 + l15) * 132 + wm + i * 16 + quad * 4) = hv;
      }
    __syncthreads();
#pragma unroll
    for (int z = 0; z < 16; ++z) {
      const int c = tid + z * 256;
      const int e = c >> 4, mc = c & 15;
      const half8 vv = *(const half8*)(smem + e * 132 + mc * 8);
      const int rg = row0 + mc * 8;
      const int b = rg / Nn, n = rg % Nn;
      const int em = eb + e;
      const int hh = em >> 6, d = em & 63;
      *(half8*)(V8 + (((size_t)(b * Hh + hh) * NC + (n >> 3)) * 64 + d) * 8) = vv;
    }
  } else {
    // Q/K: [m][e] stride 264, store 8-consecutive-d chunks
    _Float16* Ob = (tsel == 0) ? Q8 : K8;
#pragma unroll
    for (int i = 0; i < 4; ++i)
#pragma unroll
      for (int j = 0; j < 8; ++j)
#pragma unroll
        for (int r = 0; r < 4; ++r)
          smem[(wm + i * 16 + quad * 4 + r) * 264 + wn + j * 16 + l15] =
              (_Float16)acc[i][j][r];
    __syncthreads();
#pragma unroll
    for (int z = 0; z < 16; ++z) {
      const int c = tid + z * 256;
      const int ec = c >> 7, m = c & 127;
      const half8 vv = *(const half8*)(smem + m * 264 + ec * 8);
      const int rg = row0 + m;
      const int b = rg / Nn, n = rg % Nn;
      const int em = eb + ec * 8;
      const int hh = em >> 6, dc = (em >> 3) & 7;
      *(half8*)(Ob + (((size_t)(b * Hh + hh) * 8 + dc) * Nn + n) * 8) = vv;
    }
  }
}

// ---------------------------------------------------------------- proj GEMM
// Same BM=128 x BN=256 ring-3 structure; trivial f32+bias epilogue.
__global__ __launch_bounds__(256, 2) void gemm_proj(const _Float16* __restrict__ Wbuf,
                                                    const _Float16* __restrict__ Wp,
                                                    const float* __restrict__ bias,
                                                    float* __restrict__ Out) {
  __shared__ __align__(16) _Float16 smem[3 * 12288];
  const int tid = threadIdx.x;
  const int lane = tid & 63, wid = tid >> 6;
  const int l15 = lane & 15, quad = lane >> 4;
  const int L = blockIdx.x;
  const int xcd = L & 7, idx = L >> 3;
  const int v = (xcd < 4 ? xcd * 74 : 296 + (xcd - 4) * 73) + idx;
  const int bx = v % 3, by = v / 3;
  const int row0 = by * 128;
  const int e0 = bx * 256;
  const int wm = (wid >> 1) * 64, wn = (wid & 1) * 128;

  const _Float16* Ag = Wbuf + (size_t)row0 * Dd;
  const _Float16* Bg = Wp + (size_t)e0 * Dd;

  f32x4 acc[4][8];
#pragma unroll
  for (int i = 0; i < 4; ++i)
#pragma unroll
    for (int j = 0; j < 8; ++j) acc[i][j] = (f32x4)0.0f;

  const int csel = (quad ^ ((l15 >> 1) & 3)) * 8;

  auto stage = [&](int t) {
    const int kn = t * 32;
    _Float16* base = smem + (t % 3) * 12288;
#pragma unroll
    for (int j = 0; j < 6; ++j) {
      const int c = tid + j * 256;
      const int r = c >> 2;
      const int o = ((c & 3) ^ ((r >> 1) & 3)) * 8;
      const _Float16* src = (j < 2) ? (Ag + (size_t)r * Dd + kn + o)
                                    : (Bg + (size_t)(r - 128) * Dd + kn + o);
      gll16(src, base + c * 8);
    }
  };

  stage(0);
  stage(1);
  asm volatile("s_waitcnt vmcnt(6)" ::: "memory");
  asm volatile("s_barrier" ::: "memory");

  auto tile = [&](int T, int SL, bool STG, int WV) {
    if (STG) stage(T + 2);
    const _Float16* As_ = smem + SL * 12288;
    const _Float16* Bs_ = As_ + 4096;
    half8 af[4], bf[8];
#pragma unroll
    for (int m = 0; m < 4; ++m)
      af[m] = *(const half8*)(As_ + (wm + m * 16 + l15) * 32 + csel);
#pragma unroll
    for (int n = 0; n < 8; ++n)
      bf[n] = *(const half8*)(Bs_ + (wn + n * 16 + l15) * 32 + csel);
    if (WV == 6)      asm volatile("s_waitcnt vmcnt(6) lgkmcnt(0)" ::: "memory");
    else if (WV == 0) asm volatile("s_waitcnt vmcnt(0) lgkmcnt(0)" ::: "memory");
    else              asm volatile("s_waitcnt lgkmcnt(0)" ::: "memory");
    asm volatile("s_barrier" ::: "memory");
    __builtin_amdgcn_s_setprio(1);
#pragma unroll
    for (int m = 0; m < 4; ++m)
#pragma unroll
      for (int n = 0; n < 8; ++n) acc[m][n] = MFMA(af[m], bf[n], acc[m][n]);
    __builtin_amdgcn_s_setprio(0);
  };

#pragma unroll
  for (int g = 0; g < 8; ++g) {
    const int T = 3 * g;
    tile(T,     0, T < 22,     (T < 22) ? 6 : 0);
    tile(T + 1, 1, T + 1 < 22, (T + 1 < 22) ? 6 : ((T + 1 == 22) ? 0 : -1));
    tile(T + 2, 2, T + 2 < 22, (T + 2 < 22) ? 6 : ((T + 2 == 22) ? 0 : -1));
  }

#pragma unroll
  for (int j = 0; j < 8; ++j) {
    const int e = e0 + wn + j * 16 + l15;
    const float bj = bias[e];
#pragma unroll
    for (int i = 0; i < 4; ++i) {
      const int rb = row0 + wm + i * 16 + quad * 4;
#pragma unroll
      for (int r = 0; r < 4; ++r)
        Out[(size_t)(rb + r) * Dd + e] = acc[i][j][r] + bj;
    }
  }
}

// ------------------------------------------------------------ spatial attn
__global__ __launch_bounds__(256) void attn_spatial(const _Float16* __restrict__ Q8,
                                                    const _Float16* __restrict__ K8,
                                                    const _Float16* __restrict__ V8,
                                                    _Float16* __restrict__ Wbuf) {
  __shared__ __align__(16) _Float16 Vs[64 * 216];       // 27648 B
  __shared__ __align__(16) _Float16 Plds[4][16 * 232];  // 29696 B
  const int tid = threadIdx.x;
  const int lane = tid & 63, wid = tid >> 6;
  const int l15 = lane & 15, quad = lane >> 4;
  const int gid = blockIdx.x;
  const int h = gid % 6, f = (gid / 6) % Ff, b = gid / 96;
  const size_t bh = (size_t)b * Hh + h;
  const int g0 = f * Pp;
  const int off = g0 & 7;
  const int nc0 = g0 >> 3;
  const _Float16* Qp = Q8 + bh * 8 * (size_t)Nn * 8;
  const _Float16* Kp = K8 + bh * 8 * (size_t)Nn * 8;

  for (int c = tid; c < 26 * 64; c += 256) {
    const int d = c & 63, ncl = c >> 6;
    const half8 v = *(const half8*)(V8 + ((bh * NC + nc0 + ncl) * 64 + d) * 8);
    _Float16* dst = Vs + d * 216 + (8 - off) + ncl * 8;
    half4h lo, hi;
#pragma unroll
    for (int z = 0; z < 4; ++z) { lo[z] = v[z]; hi[z] = v[4 + z]; }
    *(half4h*)dst = lo;
    *(half4h*)(dst + 4) = hi;
  }
  _Float16* Pw = &Plds[wid][0];
  if (quad < 3) {  // zero P cols 208..231 (PV reads k up to 223)
    half8 z8;
#pragma unroll
    for (int z = 0; z < 8; ++z) z8[z] = (_Float16)0.0f;
    *(half8*)(Pw + l15 * 232 + 208 + quad * 8) = z8;
  }
  __syncthreads();

  half8 h8z;
#pragma unroll
  for (int z = 0; z < 8; ++z) h8z[z] = (_Float16)0.0f;

  for (int it = 0; it < 4; ++it) {
    const int qi = wid + it * 4;
    if (qi > 12) continue;
    const int qr = qi * 16 + l15;
    const int qtok = g0 + (qr < 195 ? qr : 195);
    const half8 bq0 = *(const half8*)(Qp + ((size_t)quad * Nn + qtok) * 8);
    const half8 bq1 = *(const half8*)(Qp + ((size_t)(quad + 4) * Nn + qtok) * 8);

    f32x4 ex[13];
    float rs = 0.0f;
#pragma unroll
    for (int kt = 0; kt < 13; ++kt) {
      const int krr = kt * 16 + l15;
      const int ktok = g0 + (krr < 195 ? krr : 195);
      const half8 ak0 = *(const half8*)(Kp + ((size_t)quad * Nn + ktok) * 8);
      const half8 ak1 = *(const half8*)(Kp + ((size_t)(quad + 4) * Nn + ktok) * 8);
      f32x4 t = (f32x4)0.0f;
      t = MFMA(ak0, bq0, t);
      t = MFMA(ak1, bq1, t);
      f32x4 e;
#pragma unroll
      for (int r = 0; r < 4; ++r) e[r] = __expf(t[r] * 0.125f);
      if (kt == 12 && quad >= 1) e = (f32x4)0.0f;  // keys 196..207
      ex[kt] = e;
      rs += e[0] + e[1] + e[2] + e[3];
    }
    // vectorized P^T write: 13 x ds_write_b64 instead of 52 x ds_write_b16
#pragma unroll
    for (int kt = 0; kt < 13; ++kt) {
      half4h pv;
#pragma unroll
      for (int r = 0; r < 4; ++r) pv[r] = (_Float16)ex[kt][r];
      *(half4h*)(Pw + l15 * 232 + kt * 16 + quad * 4) = pv;
    }
    rs += __shfl_xor(rs, 16);
    rs += __shfl_xor(rs, 32);
    lds_fence();

    f32x4 acc[4];
#pragma unroll
    for (int mt = 0; mt < 4; ++mt) acc[mt] = (f32x4)0.0f;
#pragma unroll
    for (int c = 0; c < 7; ++c) {
      const half8 bp = *(const half8*)(Pw + l15 * 232 + c * 32 + quad * 8);
      const int k0 = c * 32 + quad * 8;
#pragma unroll
      for (int mt = 0; mt < 4; ++mt) {
        const int d = mt * 16 + l15;
        half8 av = h8z;
        if (k0 < 196) av = *(const half8*)(Vs + d * 216 + 8 + k0);
        acc[mt] = MFMA(av, bp, acc[mt]);  // O^T[d][q]
      }
    }
    const float inv = 1.0f / rs;
    if (qr < 196) {
      _Float16* base = Wbuf + (size_t)(b * Nn + g0 + qr) * Dd + h * HD;
#pragma unroll
      for (int mt = 0; mt < 4; ++mt) {
        half4h o;
#pragma unroll
        for (int r = 0; r < 4; ++r) o[r] = (_Float16)(acc[mt][r] * inv);
        *(half4h*)(base + mt * 16 + quad * 4) = o;
      }
    }
    __builtin_amdgcn_sched_barrier(0);
  }
}

// ----------------------------------------------------------- temporal attn
__global__ __launch_bounds__(256) void attn_temporal(const _Float16* __restrict__ Q8,
                                                     const _Float16* __restrict__ K8,
                                                     const _Float16* __restrict__ V8,
                                                     _Float16* __restrict__ Wbuf) {
  __shared__ __align__(16) _Float16 Plds[4][16 * 40];
  const int tid = threadIdx.x;
  const int lane = tid & 63, wid = tid >> 6;
  const int l15 = lane & 15, quad = lane >> 4;
  const int p = blockIdx.x * 4 + wid;
  const int J0 = p << 4;
  const int b = J0 / 18816;  // H2*N
  const int rem = J0 % 18816;
  const int hh = rem / Nn;
  const int n0 = rem % Nn;   // 16-aligned
  const size_t bh = (size_t)b * Hh + 6 + hh;
  const _Float16* Qp = Q8 + bh * 8 * (size_t)Nn * 8;
  const _Float16* Kp = K8 + bh * 8 * (size_t)Nn * 8;
  _Float16* Pw = &Plds[wid][0];

  const int tok = n0 + l15;
  const half8 bq0 = *(const half8*)(Qp + ((size_t)quad * Nn + tok) * 8);
  const half8 bq1 = *(const half8*)(Qp + ((size_t)(quad + 4) * Nn + tok) * 8);
  const half8 ak0 = *(const half8*)(Kp + ((size_t)quad * Nn + tok) * 8);
  const half8 ak1 = *(const half8*)(Kp + ((size_t)(quad + 4) * Nn + tok) * 8);
  f32x4 t = (f32x4)0.0f;
  t = MFMA(ak0, bq0, t);  // St[k][q]
  t = MFMA(ak1, bq1, t);
  f32x4 e;
#pragma unroll
  for (int r = 0; r < 4; ++r) e[r] = __expf(t[r] * 0.125f);
  float rs = e[0] + e[1] + e[2] + e[3];
  rs += __shfl_xor(rs, 16);
  rs += __shfl_xor(rs, 32);

  {
    half4h pv;
#pragma unroll
    for (int r = 0; r < 4; ++r) pv[r] = (_Float16)e[r];
    *(half4h*)(Pw + l15 * 40 + quad * 4) = pv;  // one b64 instead of 4 b16
    half4h z4;
    z4.x = z4.y = z4.z = z4.w = (_Float16)0.0f;
    *(half4h*)(Pw + l15 * 40 + 16 + quad * 4) = z4;  // zero k=16..31
  }
  lds_fence();

  const half8 bp = *(const half8*)(Pw + l15 * 40 + quad * 8);  // B: P[q][k]
  half8 h8z;
#pragma unroll
  for (int z = 0; z < 8; ++z) h8z[z] = (_Float16)0.0f;

  const float inv = 1.0f / rs;
  _Float16* base = Wbuf + (size_t)(b * Nn + n0 + l15) * Dd + (6 + hh) * HD;
#pragma unroll
  for (int mt = 0; mt < 4; ++mt) {
    const int d = mt * 16 + l15;
    half8 av = h8z;
    if (quad < 2)
      av = *(const half8*)(V8 + ((bh * NC + (n0 >> 3) + quad) * 64 + d) * 8);
    f32x4 acc = (f32x4)0.0f;
    acc = MFMA(av, bp, acc);  // O^T[d][q]
    half4h o;
#pragma unroll
    for (int r = 0; r < 4; ++r) o[r] = (_Float16)(acc[r] * inv);
    *(half4h*)(base + mt * 16 + quad * 4) = o;
  }
}

// ---------------------------------------------------------------- launcher
extern "C" void kernel_launch(void* const* d_in, const int* in_sizes, int n_in,
                              void* d_out, int out_size, void* d_ws, size_t ws_size,
                              hipStream_t stream) {
  const float* x = (const float*)d_in[0];
  const float* w_qkv = (const float*)d_in[1];
  const float* w_proj = (const float*)d_in[2];
  const float* b_proj = (const float*)d_in[3];
  float* out = (float*)d_out;

  _Float16* Xh = (_Float16*)d_ws;    // 19267584 elems; reused as Wbuf
  _Float16* Q8 = Xh + 19267584;      // (b,h,dc,n,8)
  _Float16* K8 = Q8 + 19267584;
  _Float16* V8 = K8 + 19267584;      // (b,h,n/8,d,8)
  _Float16* Wqh = V8 + 19267584;     // 1769472
  _Float16* Wph = Wqh + 1769472;     // 589824

  cvt_all<<<21120, 256, 0, stream>>>(x, w_qkv, w_proj, Xh, Wqh, Wph);
  gemm_qkv<<<1764, 256, 0, stream>>>(Xh, Wqh, Q8, K8, V8);
  attn_spatial<<<768, 256, 0, stream>>>(Q8, K8, V8, Xh);
  attn_temporal<<<2352, 256, 0, stream>>>(Q8, K8, V8, Xh);
  gemm_proj<<<588, 256, 0, stream>>>(Xh, Wph, b_proj, out);
}